// Round 9
// baseline (366.662 us; speedup 1.0000x reference)
//
#include <hip/hip_runtime.h>

#define B_  2
#define C_  192
#define L_  4096
#define NH_ 8
#define HD_ 24
#define C3_ 576
#define KV_ 64
#define NSPL_ 4
#define LSPL_ (L_ / NSPL_)
#define NTS_ (LSPL_ / KV_)   // 16 tiles per block
#define HG_ 4                // heads per wave/block
#define KSTR_ 20             // K row stride in words (64B data + 16B pad)

typedef _Float16 f16;
typedef __attribute__((ext_vector_type(8))) f16 f16x8;
typedef __attribute__((ext_vector_type(16))) float f32x16;

#define L2E_ 1.4426950408889634f

__device__ __forceinline__ int pk2(float a, float b) {
    union { __fp16 h __attribute__((ext_vector_type(2))); int i; } u;
    u.h = __builtin_amdgcn_cvt_pkrtz(a, b);
    return u.i;
}
__device__ __forceinline__ int pk2_rte(float a, float b) {
    union { f16 h[2]; int i; } u;
    u.h[0] = (f16)a; u.h[1] = (f16)b;
    return u.i;
}
__device__ __forceinline__ float ex2(float x) {
    float r;
    asm("v_exp_f32 %0, %1" : "=v"(r) : "v"(x));
    return r;
}
__device__ __forceinline__ float lg2(float x) {
    float r;
    asm("v_log_f32 %0, %1" : "=v"(r) : "v"(x));
    return r;
}

union Frag { f16x8 v; int i[4]; };

#define MFMA32(A, Bx, Cc) __builtin_amdgcn_mfma_f32_32x32x16_f16((A), (Bx), (Cc), 0, 0, 0)

// ---------------------------------------------------------------------------
// QKV 1x1 conv -> packed f16 workspace.
// Q:   half2 pair-words q2[b][h][dp=0..11][L]   (pre-scaled by 8^-0.5*log2e)
// K:   key-major padded k2t[b][h][key][KSTR_=20 words]: words 0..11 = dp pairs,
//      words 12..19 = ZERO (Q-side fragment is zero there too)
// V:   plain f16 v16[b][h][d=0..31][L]; rows 24..31 never written (only feed
//      discarded O^T rows)
// ---------------------------------------------------------------------------
__global__ __launch_bounds__(256) void lin_qkv(const float* __restrict__ a,
                                               const float* __restrict__ w,
                                               const float* __restrict__ bias,
                                               unsigned int* __restrict__ q2,
                                               unsigned int* __restrict__ k2t,
                                               unsigned short* __restrict__ v16) {
    __shared__ float wl[8][C_];
    const int og  = blockIdx.x;          // 0..71 (8 out-channels each)
    const int b   = blockIdx.y >> 4;
    const int lt  = blockIdx.y & 15;
    const int tid = threadIdx.x;

    for (int e = tid; e < 8 * C_; e += 256) wl[e / C_][e % C_] = w[og * 8 * C_ + e];
    __syncthreads();

    const int l = lt * 256 + tid;
    float acc[8];
#pragma unroll
    for (int j = 0; j < 8; ++j) acc[j] = bias[og * 8 + j];

    const float* ap = a + (size_t)b * C_ * L_ + l;
#pragma unroll 2
    for (int c = 0; c < C_; ++c) {
        const float xv = ap[(size_t)c * L_];
#pragma unroll
        for (int j = 0; j < 8; ++j) acc[j] = fmaf(wl[j][c], xv, acc[j]);
    }

    const float qscale = 0.35355339059327373f * L2E_;  // heads^-0.5 * log2e
    if (og < 24) {               // Q
        const int h = og / 3, j0 = (og % 3) * 4;
        unsigned int* p = q2 + ((size_t)(b * NH_ + h) * 12 + j0) * L_ + l;
#pragma unroll
        for (int j = 0; j < 4; ++j)
            p[(size_t)j * L_] = pk2_rte(acc[2 * j] * qscale, acc[2 * j + 1] * qscale);
    } else if (og < 48) {        // K -> key-major padded
        const int og_ = og - 24;
        const int h = og_ / 3, j0 = (og_ % 3) * 4;
        unsigned int* p = k2t + ((size_t)(b * NH_ + h) * L_ + l) * KSTR_ + j0;
        int4 v;
        v.x = pk2_rte(acc[0], acc[1]); v.y = pk2_rte(acc[2], acc[3]);
        v.z = pk2_rte(acc[4], acc[5]); v.w = pk2_rte(acc[6], acc[7]);
        *(int4*)p = v;
        if (j0 == 8) {           // zero pad words 12..19 exactly once per key
            int4 z; z.x = z.y = z.z = z.w = 0;
            *(int4*)(p + 4) = z;
            *(int4*)(p + 8) = z;
        }
    } else {                     // V (32-row stride, rows 24..31 unwritten)
        const int og_ = og - 48;
        const int h = og_ / 3, d0 = (og_ % 3) * 8;
        unsigned short* p = v16 + ((size_t)(b * NH_ + h) * 32 + d0) * L_ + l;
#pragma unroll
        for (int j = 0; j < 8; ++j) {
            union { f16 hf; unsigned short us; } cv;
            cv.hf = (f16)acc[j];
            p[(size_t)j * L_] = cv.us;
        }
    }
}

// ---------------------------------------------------------------------------
// f32 per-pixel linear (output projection)
// ---------------------------------------------------------------------------
__global__ __launch_bounds__(256) void lin_kernel(const float* __restrict__ a,
                                                  const float* __restrict__ w,
                                                  const float* __restrict__ bias,
                                                  float* __restrict__ out, int OC) {
    __shared__ float wl[8][C_];
    const int og  = blockIdx.x;
    const int b   = blockIdx.y >> 4;
    const int lt  = blockIdx.y & 15;
    const int tid = threadIdx.x;

    for (int e = tid; e < 8 * C_; e += 256) wl[e / C_][e % C_] = w[og * 8 * C_ + e];
    __syncthreads();

    const int l = lt * 256 + tid;
    float acc[8];
#pragma unroll
    for (int j = 0; j < 8; ++j) acc[j] = bias[og * 8 + j];

    const float* ap = a + (size_t)b * C_ * L_ + l;
#pragma unroll 2
    for (int c = 0; c < C_; ++c) {
        const float xv = ap[(size_t)c * L_];
#pragma unroll
        for (int j = 0; j < 8; ++j) acc[j] = fmaf(wl[j][c], xv, acc[j]);
    }

    float* op = out + ((size_t)b * OC + og * 8) * L_ + l;
#pragma unroll
    for (int j = 0; j < 8; ++j) op[(size_t)j * L_] = acc[j];
}

// ---------------------------------------------------------------------------
// MFMA f16 flash attention — ZERO LDS / ZERO BARRIER version.
// All MFMA fragments load directly from global (L2-resident):
//   K-frag: one b128 at k2t[(kk+lq)*20 + 4hi (+8)]   (key-major padded rows)
//   V-frag: one b128 at v16[lq][kk + 16s + 8hi]      (d-major rows; d=lq)
// Waves fully independent -> stalls interleave instead of phase-locking.
// Wave = 32 q-rows x 4 heads (head-shared mask as C-init, 2-head ILP pairs).
// Branchless log2-domain online softmax, tree reductions.
// Grid 512: bid = ((sp*2+hg)*2+b)*32 + qt.  KV-split x4, combine merges.
// ---------------------------------------------------------------------------
__global__ __launch_bounds__(256) void attn_mfma(const unsigned int* __restrict__ q2,
                                                 const unsigned int* __restrict__ k2t,
                                                 const unsigned short* __restrict__ v16,
                                                 const float* __restrict__ mask,
                                                 unsigned short* __restrict__ po,
                                                 float* __restrict__ pms) {
    const int tid  = threadIdx.x;
    const int lane = tid & 63;
    const int wid  = tid >> 6;
    const int hi   = lane >> 5;
    const int lq   = lane & 31;
    const int bid  = blockIdx.x;
    const int qt   = bid & 31;
    const int r    = bid >> 5;
    const int b    = r & 1;
    const int hg   = (r >> 1) & 1;
    const int sp   = r >> 2;
    const int qrow = qt * 128 + wid * 32 + lq;
    const int kv0  = sp * LSPL_;
    const int hbase = hg * HG_;

    const unsigned int*   qb  = q2  + (size_t)(b * NH_ + hbase) * 12 * L_;
    const int*            kb0 = (const int*)k2t + (size_t)(b * NH_ + hbase) * L_ * KSTR_;
    const unsigned short* vb0 = v16 + (size_t)(b * NH_ + hbase) * 32 * L_;
    const float* mrow = mask + ((size_t)b * L_ + qrow) * L_;

    // Q fragments for 4 heads (zero where dpq >= 12 -> K pad contributes 0)
    int bq[HG_][8];
#pragma unroll
    for (int H = 0; H < HG_; ++H)
#pragma unroll
        for (int s = 0; s < 2; ++s)
#pragma unroll
            for (int t = 0; t < 4; ++t) {
                const int dpq = 8 * s + 4 * hi + t;
                bq[H][s * 4 + t] = (dpq < 12) ? qb[(size_t)(H * 12 + dpq) * L_ + qrow] : 0;
            }

#define MLOADX(MD, KK) do {                                                   \
    const float4* mb_ = (const float4*)(mrow + (KK));                         \
    _Pragma("unroll")                                                         \
    for (int q_ = 0; q_ < 4; ++q_) {                                          \
        MD[q_]     = mb_[2 * q_ + hi];                                        \
        MD[4 + q_] = mb_[8 + 2 * q_ + hi];                                    \
    } } while (0)

// QK^T for one head, direct-global K-frags: 4 b128 + 4 MFMA.
#define QKH(H, KK, C0, C1) do {                                               \
    Frag qf0, qf1, ka;                                                        \
    _Pragma("unroll")                                                         \
    for (int t_ = 0; t_ < 4; ++t_) { qf0.i[t_] = bq[H][t_]; qf1.i[t_] = bq[H][4 + t_]; } \
    const int* kb_ = kb0 + (size_t)(H) * L_ * KSTR_;                          \
    ka.v = *(const f16x8*)(kb_ + (size_t)((KK) + lq) * KSTR_ + 4 * hi);       \
    C0 = MFMA32(ka.v, qf0.v, mr0);                                            \
    ka.v = *(const f16x8*)(kb_ + (size_t)((KK) + lq) * KSTR_ + 8 + 4 * hi);   \
    C0 = MFMA32(ka.v, qf1.v, C0);                                             \
    ka.v = *(const f16x8*)(kb_ + (size_t)((KK) + 32 + lq) * KSTR_ + 4 * hi);  \
    C1 = MFMA32(ka.v, qf0.v, mr1);                                            \
    ka.v = *(const f16x8*)(kb_ + (size_t)((KK) + 32 + lq) * KSTR_ + 8 + 4 * hi); \
    C1 = MFMA32(ka.v, qf1.v, C1);                                             \
    } while (0)

// Branchless online softmax (log2 domain), tree reductions.
#define SMH(H, C0, C1) do {                                                   \
    float m8[8], m4[4], m2[2];                                                \
    _Pragma("unroll")                                                         \
    for (int i_ = 0; i_ < 8; ++i_)                                            \
        m8[i_] = fmaxf(fmaxf(C0[i_], C0[i_ + 8]), fmaxf(C1[i_], C1[i_ + 8])); \
    _Pragma("unroll")                                                         \
    for (int i_ = 0; i_ < 4; ++i_) m4[i_] = fmaxf(m8[i_], m8[i_ + 4]);        \
    m2[0] = fmaxf(m4[0], m4[2]); m2[1] = fmaxf(m4[1], m4[3]);                 \
    float pmax = fmaxf(m2[0], m2[1]);                                         \
    pmax = fmaxf(pmax, __shfl_xor(pmax, 32));                                 \
    const float newm_ = fmaxf(mrun[H], pmax);                                 \
    const float r_ = ex2(mrun[H] - newm_);                                    \
    mrun[H] = newm_;                                                          \
    srun[H] *= r_;                                                            \
    _Pragma("unroll")                                                         \
    for (int i_ = 0; i_ < 16; ++i_) o[H][i_] *= r_;                           \
    _Pragma("unroll")                                                         \
    for (int i_ = 0; i_ < 16; ++i_) C0[i_] = ex2(C0[i_] - newm_);             \
    _Pragma("unroll")                                                         \
    for (int i_ = 0; i_ < 16; ++i_) C1[i_] = ex2(C1[i_] - newm_);             \
    float s8[8], s4[4];                                                       \
    _Pragma("unroll")                                                         \
    for (int i_ = 0; i_ < 8; ++i_)                                            \
        s8[i_] = (C0[i_] + C0[i_ + 8]) + (C1[i_] + C1[i_ + 8]);               \
    _Pragma("unroll")                                                         \
    for (int i_ = 0; i_ < 4; ++i_) s4[i_] = s8[i_] + s8[i_ + 4];              \
    float ls = (s4[0] + s4[2]) + (s4[1] + s4[3]);                             \
    ls += __shfl_xor(ls, 32);                                                 \
    srun[H] += ls;                                                            \
    } while (0)

// PV for one head, direct-global V-frags: pack P->f16, half-exchange,
// 4 b128 + 4 MFMA.
#define PVH(H, KK, C0, C1) do {                                               \
    int wa1[4], wa2[4], sa1[4], sa2[4];                                       \
    int wb1[4], wb2[4], sb1[4], sb2[4];                                       \
    _Pragma("unroll")                                                         \
    for (int q_ = 0; q_ < 4; ++q_) {                                          \
        wa1[q_] = pk2(C0[4 * q_], C0[4 * q_ + 1]);                            \
        wa2[q_] = pk2(C0[4 * q_ + 2], C0[4 * q_ + 3]);                        \
        wb1[q_] = pk2(C1[4 * q_], C1[4 * q_ + 1]);                            \
        wb2[q_] = pk2(C1[4 * q_ + 2], C1[4 * q_ + 3]);                        \
    }                                                                         \
    _Pragma("unroll")                                                         \
    for (int q_ = 0; q_ < 4; ++q_) {                                          \
        sa1[q_] = __shfl_xor(wa1[q_], 32); sa2[q_] = __shfl_xor(wa2[q_], 32); \
        sb1[q_] = __shfl_xor(wb1[q_], 32); sb2[q_] = __shfl_xor(wb2[q_], 32); \
    }                                                                         \
    const unsigned short* vb_ = vb0 + (size_t)(H) * 32 * L_ + (size_t)lq * L_ + (KK) + 8 * hi; \
    _Pragma("unroll")                                                         \
    for (int s_ = 0; s_ < 2; ++s_) {                                          \
        const int qq_ = 2 * s_ + hi;                                          \
        Frag pb, va;                                                          \
        pb.i[0] = hi ? sa1[qq_] : wa1[qq_];                                   \
        pb.i[1] = hi ? sa2[qq_] : wa2[qq_];                                   \
        pb.i[2] = hi ? wa1[qq_] : sa1[qq_];                                   \
        pb.i[3] = hi ? wa2[qq_] : sa2[qq_];                                   \
        va.v = *(const f16x8*)(vb_ + 16 * s_);                                \
        o[H] = MFMA32(va.v, pb.v, o[H]);                                      \
        pb.i[0] = hi ? sb1[qq_] : wb1[qq_];                                   \
        pb.i[1] = hi ? sb2[qq_] : wb2[qq_];                                   \
        pb.i[2] = hi ? wb1[qq_] : sb1[qq_];                                   \
        pb.i[3] = hi ? wb2[qq_] : sb2[qq_];                                   \
        va.v = *(const f16x8*)(vb_ + 32 + 16 * s_);                           \
        o[H] = MFMA32(va.v, pb.v, o[H]);                                      \
    } } while (0)

#define COMPUTE(KK, MC) do {                                                  \
    f32x16 mr0, mr1;                                                          \
    _Pragma("unroll")                                                         \
    for (int q_ = 0; q_ < 4; ++q_) {                                          \
        mr0[4 * q_ + 0] = MC[q_].x * L2E_; mr0[4 * q_ + 1] = MC[q_].y * L2E_; \
        mr0[4 * q_ + 2] = MC[q_].z * L2E_; mr0[4 * q_ + 3] = MC[q_].w * L2E_; \
        mr1[4 * q_ + 0] = MC[4 + q_].x * L2E_; mr1[4 * q_ + 1] = MC[4 + q_].y * L2E_; \
        mr1[4 * q_ + 2] = MC[4 + q_].z * L2E_; mr1[4 * q_ + 3] = MC[4 + q_].w * L2E_; \
    }                                                                         \
    f32x16 cA0, cA1, cB0, cB1;                                                \
    QKH(0, KK, cA0, cA1);                                                     \
    QKH(1, KK, cB0, cB1);                                                     \
    SMH(0, cA0, cA1);                                                         \
    SMH(1, cB0, cB1);                                                         \
    PVH(0, KK, cA0, cA1);                                                     \
    PVH(1, KK, cB0, cB1);                                                     \
    QKH(2, KK, cA0, cA1);                                                     \
    QKH(3, KK, cB0, cB1);                                                     \
    SMH(2, cA0, cA1);                                                         \
    SMH(3, cB0, cB1);                                                         \
    PVH(2, KK, cA0, cA1);                                                     \
    PVH(3, KK, cB0, cB1);                                                     \
    } while (0)

    f32x16 o[HG_];
    float mrun[HG_], srun[HG_];
#pragma unroll
    for (int H = 0; H < HG_; ++H) {
#pragma unroll
        for (int i = 0; i < 16; ++i) o[H][i] = 0.f;
        mrun[H] = -1e30f;
        srun[H] = 0.f;
    }
    float4 mc[8], mn[8];

    MLOADX(mc, kv0);

#pragma clang loop unroll(disable)
    for (int t = 0; t < NTS_; t += 2) {
        const int kk = kv0 + t * KV_;
        MLOADX(mn, kk + KV_);
        COMPUTE(kk, mc);
        if (t + 2 < NTS_) MLOADX(mc, kk + 2 * KV_);
        COMPUTE(kk + KV_, mn);
    }

    // ---- partial epilogue per head: normalized O (f16) + lse (f32, log2) ----
#pragma unroll
    for (int H = 0; H < HG_; ++H) {
        const float inv = 1.f / srun[H];
        const float lse = mrun[H] + lg2(srun[H]);
        unsigned short* pob = po + ((size_t)((sp * B_ + b) * NH_ + hbase + H) * HD_) * L_ + qrow;
#pragma unroll
        for (int i = 0; i < 16; ++i) {
            const int d = (i & 3) + 8 * (i >> 2) + 4 * hi;
            if (d < HD_) {
                union { __fp16 hf; unsigned short us; } cv;
                cv.hf = (__fp16)(o[H][i] * inv);
                pob[(size_t)d * L_] = cv.us;
            }
        }
        if (hi == 0)
            pms[((size_t)(sp * B_ + b) * NH_ + hbase + H) * L_ + qrow] = lse;
    }
#undef MLOADX
#undef QKH
#undef SMH
#undef PVH
#undef COMPUTE
}

// ---------------------------------------------------------------------------
// Combine the 4 KV-split partials.
// ---------------------------------------------------------------------------
__global__ __launch_bounds__(256) void combine_kernel(const unsigned short* __restrict__ po,
                                                      const float* __restrict__ pms,
                                                      float* __restrict__ att) {
    const int qrow = blockIdx.x * 256 + threadIdx.x;
    const int h    = blockIdx.y;
    const int b    = blockIdx.z;

    float l[NSPL_];
#pragma unroll
    for (int s = 0; s < NSPL_; ++s)
        l[s] = pms[((size_t)(s * B_ + b) * NH_ + h) * L_ + qrow];
    float lm = l[0];
#pragma unroll
    for (int s = 1; s < NSPL_; ++s) lm = fmaxf(lm, l[s]);
    float wv[NSPL_], wsum = 0.f;
#pragma unroll
    for (int s = 0; s < NSPL_; ++s) { wv[s] = ex2(l[s] - lm); wsum += wv[s]; }
    const float inv = 1.f / wsum;

    float* op = att + ((size_t)b * C_ + h * HD_) * L_ + qrow;
#pragma unroll
    for (int d = 0; d < HD_; ++d) {
        float acc = 0.f;
#pragma unroll
        for (int s = 0; s < NSPL_; ++s) {
            union { unsigned short us; __fp16 hf; } cv;
            cv.us = po[(((size_t)(s * B_ + b) * NH_ + h) * HD_ + d) * L_ + qrow];
            acc += (float)cv.hf * wv[s];
        }
        op[(size_t)d * L_] = acc * inv;
    }
}

// ---------------------------------------------------------------------------
extern "C" void kernel_launch(void* const* d_in, const int* in_sizes, int n_in,
                              void* d_out, int out_size, void* d_ws, size_t ws_size,
                              hipStream_t stream) {
    const float* x      = (const float*)d_in[0];
    const float* mask   = (const float*)d_in[1];
    const float* w_qkv  = (const float*)d_in[2];
    const float* b_qkv  = (const float*)d_in[3];
    const float* w_proj = (const float*)d_in[4];
    const float* b_proj = (const float*)d_in[5];
    float* out = (float*)d_out;

    unsigned int*   q2  = (unsigned int*)d_ws;                                // B*8*12*L u32
    unsigned int*   k2t = q2 + (size_t)B_ * NH_ * 12 * L_;                    // B*8*L*20 u32
    unsigned short* v16 = (unsigned short*)(k2t + (size_t)B_ * NH_ * L_ * KSTR_); // B*8*32*L u16
    unsigned short* po  = v16 + (size_t)B_ * NH_ * 32 * L_;                   // 4*B*8*24*L u16
    float* pms    = (float*)(po + (size_t)NSPL_ * B_ * NH_ * HD_ * L_);       // 4*B*8*L f32
    float* ws_att = pms + (size_t)NSPL_ * B_ * NH_ * L_;                      // B*192*L f32

    lin_qkv<<<dim3(72, 32), 256, 0, stream>>>(x, w_qkv, b_qkv, q2, k2t, v16);
    attn_mfma<<<dim3(512), 256, 0, stream>>>(q2, k2t, v16, mask, po, pms);
    combine_kernel<<<dim3(16, NH_, B_), 256, 0, stream>>>(po, pms, ws_att);
    lin_kernel<<<dim3(24, 32), 256, 0, stream>>>(ws_att, w_proj, b_proj, out, C_);
}